// Round 2
// baseline (127.832 us; speedup 1.0000x reference)
//
#include <hip/hip_runtime.h>
#include <hip/hip_fp16.h>

#define HH 256
#define WW 256
#define KK 4
#define TILE 16
#define HALO 18               // 16 + 1-pixel halo each side
#define NPIX (HALO*HALO)      // 324
#define BIGF 1e10f
#define NORM_C 0.6503144f     // 1.05 / (1 + 4e^-2 + 4e^-4)
#define E2M 0.13533528f       // e^-2

// LDS strides chosen for bank-conflict-free wave access (lanes differ in tx -> pixel):
//  rgba: 20 halves/pixel (=10 dwords, 10*tx mod 32 covers all banks for b64 reads)
//  w:    26 halves/pixel (=13 dwords, coprime with 32)
//  d:    5 floats/pixel  (coprime with 32)
#define RG_STRIDE 20
#define W_STRIDE  26
#define D_STRIDE  5

__global__ __launch_bounds__(256, 4) void splat_phong(
    const float* __restrict__ texels,
    const float* __restrict__ normals,
    const float* __restrict__ pccam,
    const float* __restrict__ pcscr,
    const float* __restrict__ qdep,
    const int*   __restrict__ bgmask,
    const float* __restrict__ lpos,
    const float* __restrict__ lamb,
    const float* __restrict__ ldif,
    const float* __restrict__ lspec,
    const float* __restrict__ campos,
    const float* __restrict__ mamb,
    const float* __restrict__ mdif,
    const float* __restrict__ mspec,
    float* __restrict__ out)
{
    __shared__ __half s_rgbah[NPIX * RG_STRIDE];  // 12960 B: per item: r,g,b,alpha (halves)
    __shared__ __half s_w[NPIX * W_STRIDE];       // 16848 B: per item: wy0,wy1,wy2,wx0,wx1,wx2
    __shared__ float  s_d[NPIX * D_STRIDE];       //  6480 B: per item: depth

    const int n  = blockIdx.z;
    const int y0 = blockIdx.y * TILE;
    const int x0 = blockIdx.x * TILE;
    const int tid = threadIdx.x;

    const float lx0 = lpos[0],  ly0 = lpos[1],  lz0 = lpos[2];
    const float cx0 = campos[0], cy0 = campos[1], cz0 = campos[2];
    const float A0 = lamb[0]*mamb[0],  A1 = lamb[1]*mamb[1],  A2 = lamb[2]*mamb[2];
    const float D0 = ldif[0]*mdif[0],  D1 = ldif[1]*mdif[1],  D2 = ldif[2]*mdif[2];
    const float S0 = lspec[0]*mspec[0], S1 = lspec[1]*mspec[1], S2 = lspec[2]*mspec[2];

    // ---- Phase 1: shade 18x18x4 halo once; separable Gaussian weights precomputed ----
    for (int it = tid; it < NPIX*KK; it += 256) {
        const int k  = it & (KK-1);
        const int pi = it >> 2;
        const int hy = pi / HALO;
        const int hx = pi - hy*HALO;
        const int y = y0 - 1 + hy;
        const int x = x0 - 1 + hx;
        float r0=0.f, r1=0.f, r2=0.f, alpha=0.f;
        float wy0=0.f, wy1=0.f, wy2=0.f, wx0=0.f, wx1=0.f, wx2=0.f;
        float dep = BIGF;
        if ((unsigned)y < HH && (unsigned)x < WW) {
            const int base = ((n*HH + y)*WW + x)*KK + k;
            const float* nr = normals + (size_t)base*3;
            float nx = nr[0], ny = nr[1], nz = nr[2];
            float ri = rsqrtf(nx*nx + ny*ny + nz*nz + 1e-8f);
            nx *= ri; ny *= ri; nz *= ri;
            const float* pc = pccam + (size_t)base*3;
            const float px = pc[0], py = pc[1], pz = pc[2];
            float llx = lx0-px, lly = ly0-py, llz = lz0-pz;
            ri = rsqrtf(llx*llx + lly*lly + llz*llz + 1e-8f);
            llx *= ri; lly *= ri; llz *= ri;
            float vx = cx0-px, vy = cy0-py, vz = cz0-pz;
            ri = rsqrtf(vx*vx + vy*vy + vz*vz + 1e-8f);
            vx *= ri; vy *= ri; vz *= ri;
            const float ndl = nx*llx + ny*lly + nz*llz;
            const float rx = 2.f*ndl*nx - llx;
            const float ry = 2.f*ndl*ny - lly;
            const float rz = 2.f*ndl*nz - llz;
            float rdv = fmaxf(rx*vx + ry*vy + rz*vz, 0.f);
            const float p2 = rdv*rdv, p4 = p2*p2, p8 = p4*p4;
            const float p16 = p8*p8, p32 = p16*p16, p64 = p32*p32;
            const float ndlr = fmaxf(ndl, 0.f);
            const float* t3 = texels + (size_t)base*3;
            alpha = 1.f - (float)bgmask[base];
            r0 = t3[0]*(A0 + D0*ndlr) + S0*p64;
            r1 = t3[1]*(A1 + D1*ndlr) + S1*p64;
            r2 = t3[2]*(A2 + D2*ndlr) + S2*p64;
            const float2 sc = *(const float2*)(pcscr + (size_t)base*2);
            const float jy = sc.x - ((float)y + 0.5f);
            const float jx = sc.y - ((float)x + 0.5f);
            // separable Gaussian: exp(-2(j-delta)^2) = exp(-2j^2) * e^{-2*delta^2} * exp(4*j*delta)
            const float ey = __expf(-2.f*jy*jy) * (NORM_C * alpha);  // fold norm & alpha once
            const float uyp = __expf(4.f*jy), uym = __expf(-4.f*jy);
            wy0 = ey * E2M * uym;  wy1 = ey;  wy2 = ey * E2M * uyp;
            const float ex = __expf(-2.f*jx*jx);
            const float uxp = __expf(4.f*jx), uxm = __expf(-4.f*jx);
            wx0 = ex * E2M * uxm;  wx1 = ex;  wx2 = ex * E2M * uxp;
            dep = qdep[base];
        }
        const int roff = pi*RG_STRIDE + k*4;
        *(__half2*)&s_rgbah[roff]   = __floats2half2_rn(r0, r1);
        *(__half2*)&s_rgbah[roff+2] = __floats2half2_rn(r2, alpha);
        const int woff = pi*W_STRIDE + k*6;
        *(__half2*)&s_w[woff]   = __floats2half2_rn(wy0, wy1);
        *(__half2*)&s_w[woff+2] = __floats2half2_rn(wy2, wx0);
        *(__half2*)&s_w[woff+4] = __floats2half2_rn(wx1, wx2);
        s_d[pi*D_STRIDE + k] = dep;
    }
    __syncthreads();

    // ---- Phase 2: one thread per output pixel, gather 9 neighbors x 4 layers ----
    const int ty = tid >> 4;
    const int tx = tid & 15;
    const int opix = (ty+1)*HALO + (tx+1);
    const float q0 = s_d[opix*D_STRIDE+0], q1 = s_d[opix*D_STRIDE+1];
    const float q2 = s_d[opix*D_STRIDE+2], q3 = s_d[opix*D_STRIDE+3];

    // per class: r,g,b,wsum  (alpha accum == wsum since wgt already carries alpha in {0,1})
    float fg0=0,fg1=0,fg2=0,fgw=0, sf0=0,sf1=0,sf2=0,sfw=0, bg0=0,bg1=0,bg2=0,bgw=0;

    #pragma unroll
    for (int d = 0; d < 9; ++d) {
        const int dy = d/3 - 1;
        const int dx = d - (d/3)*3 - 1;
        const int ppix = (ty+1-dy)*HALO + (tx+1-dx);   // neighbor p = gather - (dy,dx)
        const int pd_b = ppix*D_STRIDE;
        const float pd0 = s_d[pd_b], pd1 = s_d[pd_b+1], pd2 = s_d[pd_b+2], pd3 = s_d[pd_b+3];
        const float ptop = pd0;
        float dqm = fabsf(ptop - q0); int lq = 0;
        float t;
        t = fabsf(ptop - q1); if (t < dqm) { dqm = t; lq = 1; }
        t = fabsf(ptop - q2); if (t < dqm) { dqm = t; lq = 2; }
        t = fabsf(ptop - q3); if (t < dqm) { dqm = t; lq = 3; }
        float dpm = fabsf(q0 - pd0); int lp = 0;
        t = fabsf(q0 - pd1); if (t < dpm) { dpm = t; lp = 1; }
        t = fabsf(q0 - pd2); if (t < dpm) { dpm = t; lp = 2; }
        t = fabsf(q0 - pd3); if (t < dpm) { dpm = t; lp = 3; }
        const int occ = (dqm <= dpm) ? lq : -lp;
        const int wy_i = dy + 1, wx_i = dx + 1;
        #pragma unroll
        for (int k = 0; k < KK; ++k) {
            const int level = k + occ;
            const int woff = ppix*W_STRIDE + k*6;
            const float wgt = __half2float(__hmul(s_w[woff + wy_i], s_w[woff + 3 + wx_i]));
            const int roff = ppix*RG_STRIDE + k*4;
            const __half2 h01 = *(const __half2*)&s_rgbah[roff];
            const __half2 h23 = *(const __half2*)&s_rgbah[roff+2];
            const float2 c01 = __half22float2(h01);
            const float2 c23 = __half22float2(h23);
            const float wf = (level <  0) ? wgt : 0.f;
            const float ws = (level == 0) ? wgt : 0.f;
            const float wb = (level >  0) ? wgt : 0.f;
            fg0 += c01.x*wf; fg1 += c01.y*wf; fg2 += c23.x*wf; fgw += wf;
            sf0 += c01.x*ws; sf1 += c01.y*ws; sf2 += c23.x*ws; sfw += ws;
            bg0 += c01.x*wb; bg1 += c01.y*wb; bg2 += c23.x*wb; bgw += wb;
            (void)c23.y; // alpha carried implicitly by w-sums
        }
    }

    const float ifg = 1.f / fmaxf(fgw, 1e-10f);
    const float isf = 1.f / fmaxf(sfw, 1e-10f);
    const float ibg = 1.f / fmaxf(bgw, 1e-10f);
    float o0 = bg0*ibg, o1 = bg1*ibg, o2 = bg2*ibg, o3 = bgw*ibg;
    const float sa = sfw*isf;
    o0 = sf0*isf + (1.f - sa)*o0;
    o1 = sf1*isf + (1.f - sa)*o1;
    o2 = sf2*isf + (1.f - sa)*o2;
    o3 = sa      + (1.f - sa)*o3;
    const float fa = fgw*ifg;
    o0 = fg0*ifg + (1.f - fa)*o0;
    o1 = fg1*ifg + (1.f - fa)*o1;
    o2 = fg2*ifg + (1.f - fa)*o2;
    o3 = fa      + (1.f - fa)*o3;
    const float bgc = 1.f - o3;   // BG_COLOR = (1,1,1)
    const float4 res = make_float4(o0 + bgc, o1 + bgc, o2 + bgc, o3);

    const int y = y0 + ty, x = x0 + tx;
    float4* op = (float4*)(out + (size_t)((n*HH + y)*WW + x)*4);
    *op = res;
}

extern "C" void kernel_launch(void* const* d_in, const int* in_sizes, int n_in,
                              void* d_out, int out_size, void* d_ws, size_t ws_size,
                              hipStream_t stream) {
    const int N = in_sizes[4] / (HH*WW*KK);   // q_depth is (N,H,W,K)
    dim3 grid(WW/TILE, HH/TILE, N);
    splat_phong<<<grid, dim3(256), 0, stream>>>(
        (const float*)d_in[0],   // texels
        (const float*)d_in[1],   // pixel_normals
        (const float*)d_in[2],   // pixel_coords_cameras
        (const float*)d_in[3],   // pixel_coords_screen
        (const float*)d_in[4],   // q_depth
        (const int*  )d_in[5],   // background_mask
        (const float*)d_in[6],   // light_position
        (const float*)d_in[7],   // light_ambient
        (const float*)d_in[8],   // light_diffuse
        (const float*)d_in[9],   // light_specular
        (const float*)d_in[10],  // camera_position
        (const float*)d_in[11],  // mat_ambient
        (const float*)d_in[12],  // mat_diffuse
        (const float*)d_in[13],  // mat_specular
        (float*)d_out);
}